// Round 13
// baseline (114.486 us; speedup 1.0000x reference)
//
#include <hip/hip_runtime.h>
#include <hip/hip_bf16.h>

typedef __attribute__((ext_vector_type(8))) short short8_t;
typedef __attribute__((ext_vector_type(4))) float f32x4;

#define BATCH 16
#define CIN   512
#define COUT  512
#define TT    4096
#define BKT   64
#define NS    64     // total steps per block: 8 t-tiles x 8 k-chunks

// pack 2 f32 -> u32 of 2 bf16 (RNE); pairs into v_cvt_pk_bf16_f32
__device__ __forceinline__ uint pk2(float a, float b) {
    ushort lo = __builtin_bit_cast(ushort, __float2bfloat16(a));
    ushort hi = __builtin_bit_cast(ushort, __float2bfloat16(b));
    return (uint)lo | ((uint)hi << 16);
}

#define SCHEDB()    __builtin_amdgcn_sched_barrier(0)
#define WAIT_VM4()  do { asm volatile("s_waitcnt vmcnt(4)" ::: "memory"); SCHEDB(); } while (0)
#define WAIT_VM0()  do { asm volatile("s_waitcnt vmcnt(0)" ::: "memory"); SCHEDB(); } while (0)
#define WAIT_VM8()  do { asm volatile("s_waitcnt vmcnt(8)" ::: "memory"); SCHEDB(); } while (0)
#define WAIT_LGKM() do { asm volatile("s_waitcnt lgkmcnt(0)" ::: "memory"); SCHEDB(); } while (0)
#define RAW_BARRIER() do { __builtin_amdgcn_s_barrier(); SCHEDB(); } while (0)

// ---------------------------------------------------------------------------
// Pre-pass: W (fp32 [512][512]) -> bf16 MFMA A-fragment order (verified R5-R12):
//   Wb[bm][ksg][g][r][8k], bm=m>>4, r=m&15, ksg=k>>5, g=(k>>3)&3
// ---------------------------------------------------------------------------
extern "C" __global__ __launch_bounds__(256)
void wconv(const float* __restrict__ W, ushort* __restrict__ Wb)
{
    const int i  = blockIdx.x * 256 + threadIdx.x;   // [0, 65536)
    const int m  = i >> 7;
    const int k0 = (i & 127) * 4;
    const float4 v = *(const float4*)(W + (size_t)m * CIN + k0);
    const int bm = m >> 4, r = m & 15;
    const int ksg = k0 >> 5, g = (k0 >> 3) & 3, k7 = k0 & 7;
    uint2 q;
    q.x = pk2(v.x, v.y);
    q.y = pk2(v.z, v.w);
    *(uint2*)&Wb[(size_t)bm * 8192 + ksg * 512 + g * 128 + r * 8 + k7] = q;
}

// ---------------------------------------------------------------------------
// Persistent-A GEMM: 512 blocks (2/CU). Block = 128m x 512t-chunk, 4 waves
// (wave 32m). A for the FULL K=512 lives in 128 VGPR/lane (af[16][2]),
// loaded once from Wb -> K-loop has ZERO global A loads.
// Block loops 8 t-tiles of 64t; per t-tile 8 K-steps (BKT=64). Global step
// s = tt*8+kt in [0,64). B pipeline (all patterns R10-12 verified 0-conflict):
//   STAGE(s+3) -> RAW[s%3] (gload_lds fp32, issued POST-barrier: RAW[s%3]
//   was freed by CVT(s) one barrier ago) ; CVT(s+1): RAW->BF bf16 one step
//   ahead (read-early/write-late around MFMA) ; MFMA(s) reads BF[s&1].
//   vmcnt(4) retires G(s+1); G(s+2),G(s+3) stay in flight (~2 steps cover).
// LDS: RAW 3x16 KiB + BF 2x8 KiB = 64 KiB -> 2 blocks/CU.
// ---------------------------------------------------------------------------
template<bool WSB>
__global__ __launch_bounds__(256)
void conv2x1_gemm(const float* __restrict__ pre, const float* __restrict__ W,
                  const ushort* __restrict__ Wb,
                  const float* __restrict__ bias, float* __restrict__ out)
{
    __shared__ float  RAW[3][BKT * 64];      // 3 x 16 KiB fp32 ring
    __shared__ ushort BF [2][8 * 64 * 8];    // 2 x 8 KiB bf16 granules [p][t][8k]

    const int tid  = threadIdx.x;
    const int lane = tid & 63;
    const int wv   = tid >> 6;          // wave = 32m strip [0,4)
    const int g    = lane >> 4;
    const int l15  = lane & 15;

    // XCD-chunked bijective swizzle (512 = 8*64): consecutive ids share the
    // B t-chunk (same bb,tch) across the 4 m-strips on one XCD's L2.
    const int id     = ((blockIdx.x & 7) << 6) | (blockIdx.x >> 3);
    const int mstrip = id & 3;
    const int tch    = (id >> 2) & 7;
    const int bb     = id >> 5;

    const int m0    = mstrip << 7;   // [0,512) step 128
    const int tbase = tch << 9;      // [0,4096) step 512

    const float* preB = pre + (size_t)bb * ((size_t)CIN * TT);
    const int bmBase  = (m0 >> 4) + wv * 2;   // Wb block-row for this wave

    // ---------------- persistent A: full K in registers ----------------
    short8_t af[16][2];   // [ksg][mi] -- 128 VGPR
    if constexpr (WSB) {
#pragma unroll
        for (int ksg = 0; ksg < 16; ++ksg)
#pragma unroll
            for (int mi = 0; mi < 2; ++mi)
                af[ksg][mi] = *(const short8_t*)(Wb + (size_t)(bmBase + mi) * 8192
                                                 + ksg * 512 + g * 128 + l15 * 8);
    } else {
#pragma unroll
        for (int ksg = 0; ksg < 16; ++ksg)
#pragma unroll
            for (int mi = 0; mi < 2; ++mi) {
                const float* ab = W + (size_t)(m0 + wv*32 + mi*16 + l15) * CIN + ksg*32 + g*8;
                const float4 u0 = *(const float4*)ab;
                const float4 u1 = *(const float4*)(ab + 4);
                uint4 qq;
                qq.x = pk2(u0.x, u0.y); qq.y = pk2(u0.z, u0.w);
                qq.z = pk2(u1.x, u1.y); qq.w = pk2(u1.z, u1.w);
                af[ksg][mi] = __builtin_bit_cast(short8_t, qq);
            }
    }

    float bv[2][4];
#pragma unroll
    for (int mi = 0; mi < 2; ++mi)
#pragma unroll
        for (int r = 0; r < 4; ++r)
            bv[mi][r] = bias[m0 + wv*32 + g*4 + mi*16 + r];

    float f[16];   // CVT staging (read early, write late)

    // ---- B stage step S: 4 gload_lds (16B/lane); RAW[S%3] linear [64k][64t] ----
#define STAGE(S) do { \
    const int kc = ((S) & 7) * BKT; \
    const int tc = tbase + (((S) >> 3) << 6); \
    _Pragma("unroll") \
    for (int i = 0; i < 4; ++i) { \
        const int krow = wv*16 + i*4 + (lane >> 4); \
        const float* gsrc = preB + (size_t)(kc + krow) * TT + tc + ((lane & 15) << 2); \
        float* ldst = &RAW[(S) % 3][(wv*16 + i*4)*64 + lane*4]; \
        __builtin_amdgcn_global_load_lds((const __attribute__((address_space(1))) void*)gsrc, \
                                         (__attribute__((address_space(3))) void*)ldst, 16, 0, 0); \
    } } while (0)

    // ---- CVT read: 16 b32 column reads (2-way, measured-free R10-12) ----
#define CVT_READ(S) do { \
    const int ct = tid & 63; \
    _Pragma("unroll") \
    for (int j = 0; j < 16; ++j) \
        f[j] = RAW[(S) % 3][(wv*16 + j) * 64 + ct]; \
    } while (0)

    // ---- CVT write: 2 b128 granule writes (wave-contiguous 1KB, 0-conflict) ----
#define CVT_WRITE(S) do { \
    const int ct = tid & 63; \
    _Pragma("unroll") \
    for (int h = 0; h < 2; ++h) { \
        uint4 q; \
        q.x = pk2(f[h*8+0], f[h*8+1]); \
        q.y = pk2(f[h*8+2], f[h*8+3]); \
        q.z = pk2(f[h*8+4], f[h*8+5]); \
        q.w = pk2(f[h*8+6], f[h*8+7]); \
        *(uint4*)&BF[(S) & 1][(wv*2 + h) * 512 + ct * 8] = q; \
    } } while (0)

    // ---- MFMA step: 8 b128 frag reads + 16 MFMA; A from registers ----
#define MFMA_STEP(S, KT) do { \
    __builtin_amdgcn_s_setprio(1); \
    _Pragma("unroll") \
    for (int ks = 0; ks < 2; ++ks) { \
        short8_t bf[4]; \
        _Pragma("unroll") \
        for (int ni = 0; ni < 4; ++ni) \
            bf[ni] = *(const short8_t*)&BF[(S) & 1][(ks*4 + g) * 512 + (ni*16 + l15) * 8]; \
        _Pragma("unroll") \
        for (int mi = 0; mi < 2; ++mi) \
            _Pragma("unroll") \
            for (int ni = 0; ni < 4; ++ni) \
                acc[mi][ni] = __builtin_amdgcn_mfma_f32_16x16x32_bf16(af[(KT)*2+ks][mi], bf[ni], acc[mi][ni], 0, 0, 0); \
    } \
    __builtin_amdgcn_s_setprio(0); \
    } while (0)

    // -------- prologue: A loads above (oldest), then 3 stage tiles --------
    STAGE(0); STAGE(1); STAGE(2);   // 12 G in flight (+ A loads older)
    WAIT_VM8();                      // retire A(all) + G(0); G(1),G(2) in flight
    RAW_BARRIER();
    CVT_READ(0);
    CVT_WRITE(0);                    // RAW[0] -> BF[0]

    f32x4 acc[2][4];
#pragma unroll
    for (int i = 0; i < 2; ++i)
#pragma unroll
        for (int j = 0; j < 4; ++j) acc[i][j] = (f32x4)0.0f;

    float* outB = out + (size_t)bb * ((size_t)COUT * TT);

    // -------- main loop: 8 t-tiles x 8 K-steps --------
    for (int tt = 0; tt < 8; ++tt) {
#pragma unroll
        for (int kt = 0; kt < 8; ++kt) {
            const int s = tt * 8 + kt;
            if (s + 2 < NS) WAIT_VM4();   // retire G(s+1); keep G(s+2[,s+3])
            else            WAIT_VM0();   // tail drain
            WAIT_LGKM();                  // CVT writes/frag reads retired
            RAW_BARRIER();                // BF[s&1] + RAW[(s+1)%3] visible
            if (s + 3 < NS) STAGE(s + 3); // into RAW[s%3] (freed by CVT(s))
            if (s + 1 < NS) CVT_READ(s + 1);
            MFMA_STEP(s, kt);
            if (s + 1 < NS) CVT_WRITE(s + 1);
        }

        // ---- per-t-tile epilogue: out = 2*(acc + bias); re-zero acc ----
        const int orow = m0 + wv*32 + g*4;
        const int tcol = tbase + tt*64;
#pragma unroll
        for (int mi = 0; mi < 2; ++mi) {
#pragma unroll
            for (int ni = 0; ni < 4; ++ni) {
                const int t = tcol + ni*16 + l15;
#pragma unroll
                for (int r = 0; r < 4; ++r) {
                    const int o = orow + mi*16 + r;
                    outB[(size_t)o * TT + t] = 2.0f * (acc[mi][ni][r] + bv[mi][r]);
                }
                acc[mi][ni] = (f32x4)0.0f;
            }
        }
    }
}

extern "C" void kernel_launch(void* const* d_in, const int* in_sizes, int n_in,
                              void* d_out, int out_size, void* d_ws, size_t ws_size,
                              hipStream_t stream)
{
    const float* pre  = (const float*)d_in[0];   // [16, 512, 4096] fp32
    const float* Wp   = (const float*)d_in[1];   // [512, 512] fp32
    const float* bias = (const float*)d_in[2];   // [512] fp32
    float* out = (float*)d_out;                  // [16, 512, 4096] fp32

    const size_t wb_bytes = (size_t)COUT * CIN * sizeof(ushort);   // 512 KiB

    const dim3 grid(512);    // 16 b x 4 m-strips x 8 t-chunks
    const dim3 block(256);

    if (ws_size >= wb_bytes) {
        ushort* Wb = (ushort*)d_ws;
        hipLaunchKernelGGL(wconv, dim3(256), dim3(256), 0, stream, Wp, Wb);
        hipLaunchKernelGGL((conv2x1_gemm<true>), grid, block, 0, stream,
                           pre, Wp, Wb, bias, out);
    } else {
        hipLaunchKernelGGL((conv2x1_gemm<false>), grid, block, 0, stream,
                           pre, Wp, (const ushort*)nullptr, bias, out);
    }
}

// Round 14
// 74.410 us; speedup vs baseline: 1.5386x; 1.5386x over previous
//
#include <hip/hip_runtime.h>
#include <hip/hip_bf16.h>

typedef __attribute__((ext_vector_type(8))) short short8_t;
typedef __attribute__((ext_vector_type(4))) float f32x4;

#define BATCH 16
#define CIN   512
#define COUT  512
#define TT    4096
#define BKT   32
#define NKT   16     // CIN / BKT

// pack 2 f32 -> u32 of 2 bf16 (RNE); pairs into v_cvt_pk_bf16_f32
__device__ __forceinline__ uint pk2(float a, float b) {
    ushort lo = __builtin_bit_cast(ushort, __float2bfloat16(a));
    ushort hi = __builtin_bit_cast(ushort, __float2bfloat16(b));
    return (uint)lo | ((uint)hi << 16);
}

#define SCHEDB()    __builtin_amdgcn_sched_barrier(0)
#define WAIT_VM0()  do { asm volatile("s_waitcnt vmcnt(0)" ::: "memory"); SCHEDB(); } while (0)
#define WAIT_VM4()  do { asm volatile("s_waitcnt vmcnt(4)" ::: "memory"); SCHEDB(); } while (0)
#define WAIT_VM6()  do { asm volatile("s_waitcnt vmcnt(6)" ::: "memory"); SCHEDB(); } while (0)
#define WAIT_VM8()  do { asm volatile("s_waitcnt vmcnt(8)" ::: "memory"); SCHEDB(); } while (0)
#define WAIT_LGKM() do { asm volatile("s_waitcnt lgkmcnt(0)" ::: "memory"); SCHEDB(); } while (0)
#define RAW_BARRIER() do { __builtin_amdgcn_s_barrier(); SCHEDB(); } while (0)

// ---------------------------------------------------------------------------
// Pre-pass: W (fp32 [512][512]) -> bf16 MFMA A-fragment order (verified R5-R13):
//   Wb[bm][ksg][g][r][8k], bm=m>>4, r=m&15, ksg=k>>5, g=(k>>3)&3
// ---------------------------------------------------------------------------
extern "C" __global__ __launch_bounds__(256)
void wconv(const float* __restrict__ W, ushort* __restrict__ Wb)
{
    const int i  = blockIdx.x * 256 + threadIdx.x;   // [0, 65536)
    const int m  = i >> 7;
    const int k0 = (i & 127) * 4;
    const float4 v = *(const float4*)(W + (size_t)m * CIN + k0);
    const int bm = m >> 4, r = m & 15;
    const int ksg = k0 >> 5, g = (k0 >> 3) & 3, k7 = k0 & 7;
    uint2 q;
    q.x = pk2(v.x, v.y);
    q.y = pk2(v.z, v.w);
    *(uint2*)&Wb[(size_t)bm * 8192 + ksg * 512 + g * 128 + r * 8 + k7] = q;
}

// ---------------------------------------------------------------------------
// Fused GEMM (R11 + depth-3 B prefetch): tile 256m x 64t, BKT=32 (16 steps),
// 4 waves (wave 64m x 64t, 16 MFMA/step). B pipeline sub-blocks identical to
// R10-R12 (measured 0-conflict):
//   STAGE(kt+3) -> RAW[(kt+3)%4] fp32 via gload_lds (2 iters of cover);
//   CVT one tile ahead (read-early / write-late around MFMA);
//   counted vmcnt + raw s_barrier; steady vmcnt(8) retires {A(kt), G(kt+1)},
//   leaving {A(kt+1), G(kt+2), G(kt+3)} = 8 in flight across the barrier.
// LDS: RAW 4 x 8 KiB + BF 2 x 4 KiB = 40 KiB -> 4 blocks/CU.
// ---------------------------------------------------------------------------
template<bool WSB>
__global__ __launch_bounds__(256)
void conv2x1_gemm(const float* __restrict__ pre, const float* __restrict__ W,
                  const ushort* __restrict__ Wb,
                  const float* __restrict__ bias, float* __restrict__ out)
{
    __shared__ float  RAW[4][BKT * 64];      // 4 x 8 KiB fp32 ring
    __shared__ ushort BF [2][4 * 64 * 8];    // 2 x 4 KiB bf16 granules [p][t][8k]

    const int tid  = threadIdx.x;
    const int lane = tid & 63;
    const int wv   = tid >> 6;          // wave = 64m strip [0,4); cvt k-octet
    const int g    = lane >> 4;
    const int l15  = lane & 15;

    // XCD-chunked bijective swizzle (2048 = 8*256); consecutive ids share a
    // B-panel (same bb, ti) on one XCD's L2.
    const int id   = ((blockIdx.x & 7) << 8) | (blockIdx.x >> 3);
    const int mblk = id & 1;
    const int ti   = (id >> 1) & 63;
    const int bb   = id >> 7;

    const int m0 = mblk << 8;   // {0, 256}
    const int t0 = ti << 6;     // [0,4096) step 64

    const float* preB   = pre + (size_t)bb * ((size_t)CIN * TT);
    const int    bmBase = (m0 >> 4) + wv * 4;

    f32x4 acc[4][4];
#pragma unroll
    for (int i = 0; i < 4; ++i)
#pragma unroll
        for (int j = 0; j < 4; ++j) acc[i][j] = (f32x4)0.0f;

    short8_t afA[4], afB[4];
    float    f[8];   // CVT staging (read early, write late)

    // ---- B stage: 2 gload_lds (16B) per thread; RAW[J%4] linear [32k][64t] ----
#define STAGE(J) do { \
    _Pragma("unroll") \
    for (int i = 0; i < 2; ++i) { \
        const int krow = wv*8 + i*4 + (lane >> 4); \
        const float* gsrc = preB + (size_t)((J)*BKT + krow) * TT + t0 + ((lane & 15) << 2); \
        float* ldst = &RAW[(J) % 4][(wv*128 + i*64 + lane) * 4]; \
        __builtin_amdgcn_global_load_lds((const __attribute__((address_space(1))) void*)gsrc, \
                                         (__attribute__((address_space(3))) void*)ldst, 16, 0, 0); \
    } } while (0)

    // ---- A fragments for step KT (one ksg per step since BKT=32) ----
#define LOAD_A(KT, AF) do { \
    if constexpr (WSB) { \
        _Pragma("unroll") \
        for (int mi = 0; mi < 4; ++mi) \
            AF[mi] = *(const short8_t*)(Wb + (size_t)(bmBase + mi) * 8192 \
                                        + (KT) * 512 + g * 128 + l15 * 8); \
    } else { \
        _Pragma("unroll") \
        for (int mi = 0; mi < 4; ++mi) { \
            const float* ab = W + (size_t)(m0 + wv*64 + mi*16 + l15) * CIN + (KT)*BKT + g*8; \
            const float4 u0 = *(const float4*)ab; \
            const float4 u1 = *(const float4*)(ab + 4); \
            uint4 qq; \
            qq.x = pk2(u0.x, u0.y); qq.y = pk2(u0.z, u0.w); \
            qq.z = pk2(u1.x, u1.y); qq.w = pk2(u1.z, u1.w); \
            AF[mi] = __builtin_bit_cast(short8_t, qq); \
        } \
    } } while (0)

    // ---- CVT read: 8 b32 column reads (2-way bank, measured-free R10-12) ----
#define CVT_READ(J) do { \
    const int ct = tid & 63; \
    _Pragma("unroll") \
    for (int j = 0; j < 8; ++j) \
        f[j] = RAW[(J) % 4][(wv*8 + j) * 64 + ct]; \
    } while (0)

    // ---- CVT write: 1 b128 granule write (wave-contiguous 1KB, 0-conflict) ----
#define CVT_WRITE(J) do { \
    const int ct = tid & 63; \
    uint4 q; \
    q.x = pk2(f[0], f[1]); \
    q.y = pk2(f[2], f[3]); \
    q.z = pk2(f[4], f[5]); \
    q.w = pk2(f[6], f[7]); \
    *(uint4*)&BF[(J) & 1][wv * 512 + ct * 8] = q; \
    } while (0)

    // ---- MFMA step: 4 b128 frag reads (16-lane contiguous ✓) + 16 MFMA ----
#define MFMA_STEP(J, AF) do { \
    __builtin_amdgcn_s_setprio(1); \
    short8_t bf[4]; \
    _Pragma("unroll") \
    for (int ni = 0; ni < 4; ++ni) \
        bf[ni] = *(const short8_t*)&BF[(J) & 1][g * 512 + (ni*16 + l15) * 8]; \
    _Pragma("unroll") \
    for (int mi = 0; mi < 4; ++mi) \
        _Pragma("unroll") \
        for (int ni = 0; ni < 4; ++ni) \
            acc[mi][ni] = __builtin_amdgcn_mfma_f32_16x16x32_bf16(AF[mi], bf[ni], acc[mi][ni], 0, 0, 0); \
    __builtin_amdgcn_s_setprio(0); \
    } while (0)

    // -------- prologue: G(0..2) + A(0); FIFO = [G0:2, G1:2, G2:2, A0:4] --------
    STAGE(0);
    STAGE(1);
    STAGE(2);
    LOAD_A(0, afA);
    WAIT_VM8();               // retire G(0); leave {G1, G2, A0} in flight
    RAW_BARRIER();
    CVT_READ(0);
    CVT_WRITE(0);             // RAW[0] -> BF[0]

    // -------- main loop --------
    // steady FIFO before wait: G(kt+1):2, G(kt+2):2, A(kt):4 | A(kt+1):4, G(kt+3):2
#pragma unroll
    for (int kt = 0; kt < NKT; ++kt) {
        if (kt + 1 < NKT) {
            if ((kt & 1) == 0) LOAD_A(kt + 1, afB);
            else               LOAD_A(kt + 1, afA);
        }
        if (kt + 3 < NKT) STAGE(kt + 3);
        // wait schedule (hand-verified FIFO arithmetic, incl. ramp/tail):
        if      (kt == 0)  WAIT_VM6();   // retire {G1, G2(early), A0}
        else if (kt <= 12) WAIT_VM8();   // retire {A(kt), G(kt+1)}
        else if (kt == 13) WAIT_VM6();
        else if (kt == 14) WAIT_VM4();
        else               WAIT_VM0();
        WAIT_LGKM();                     // CVT writes / frag reads retired
        RAW_BARRIER();                   // BF[kt&1] + RAW[(kt+1)%4] visible
        if (kt + 1 < NKT) CVT_READ(kt + 1);   // issue early: latency under MFMA
        if ((kt & 1) == 0) MFMA_STEP(kt, afA);
        else               MFMA_STEP(kt, afB);
        if (kt + 1 < NKT) CVT_WRITE(kt + 1);
    }

    // -------- epilogue: out = 2*(acc + bias) --------
    const int orow = m0 + wv*64 + g*4;     // + mi*16 + r
    float bv[4][4];
#pragma unroll
    for (int mi = 0; mi < 4; ++mi)
#pragma unroll
        for (int r = 0; r < 4; ++r)
            bv[mi][r] = bias[orow + mi*16 + r];

    float* outB = out + (size_t)bb * ((size_t)COUT * TT);
#pragma unroll
    for (int mi = 0; mi < 4; ++mi) {
#pragma unroll
        for (int ni = 0; ni < 4; ++ni) {
            const int t = t0 + ni*16 + l15;
#pragma unroll
            for (int r = 0; r < 4; ++r) {
                const int o = orow + mi*16 + r;
                outB[(size_t)o * TT + t] = 2.0f * (acc[mi][ni][r] + bv[mi][r]);
            }
        }
    }
}

extern "C" void kernel_launch(void* const* d_in, const int* in_sizes, int n_in,
                              void* d_out, int out_size, void* d_ws, size_t ws_size,
                              hipStream_t stream)
{
    const float* pre  = (const float*)d_in[0];   // [16, 512, 4096] fp32
    const float* Wp   = (const float*)d_in[1];   // [512, 512] fp32
    const float* bias = (const float*)d_in[2];   // [512] fp32
    float* out = (float*)d_out;                  // [16, 512, 4096] fp32

    const size_t wb_bytes = (size_t)COUT * CIN * sizeof(ushort);   // 512 KiB

    const dim3 grid(BATCH * 2 * 64);   // 16 b x 2 m-tiles x 64 t-tiles = 2048
    const dim3 block(256);

    if (ws_size >= wb_bytes) {
        ushort* Wb = (ushort*)d_ws;
        hipLaunchKernelGGL(wconv, dim3(256), dim3(256), 0, stream, Wp, Wb);
        hipLaunchKernelGGL((conv2x1_gemm<true>), grid, block, 0, stream,
                           pre, Wp, Wb, bias, out);
    } else {
        hipLaunchKernelGGL((conv2x1_gemm<false>), grid, block, 0, stream,
                           pre, Wp, (const ushort*)nullptr, bias, out);
    }
}